// Round 12
// baseline (785.347 us; speedup 1.0000x reference)
//
#include <hip/hip_runtime.h>

#define N_NODES 100000
#define N_EDGES 3200000
#define FEAT 64
#define NUM_RELS 16
#define CAP 64
#define OVF_CAP 32768
#define RANGES_W 4
#define NODES_PER_W 25000       // N_NODES / RANGES_W exact
#define FILL_BLOCKS 1024
#define AGG_G 4                 // nodes per agg2 block (1 per wave)
#define AGG_BLOCKS (NODES_PER_W / AGG_G)   // 6250
#define HS_STRIDE 1028          // floats; 4112 B: 16B-aligned, 2-way banks only

typedef float f32x4 __attribute__((ext_vector_type(4)));
typedef float f32x16 __attribute__((ext_vector_type(16)));
typedef short s16x8 __attribute__((ext_vector_type(8)));
typedef int   i32x2 __attribute__((ext_vector_type(2)));
typedef int   i32x4 __attribute__((ext_vector_type(4)));

__device__ __forceinline__ unsigned short f32_to_bf16_rne(float x) {
    unsigned int u = __float_as_uint(x);
    unsigned int r = (u + 0x7fffu + ((u >> 16) & 1u)) >> 16;
    return (unsigned short)r;
}
__device__ __forceinline__ float bf16_to_f32(unsigned short s) {
    return __uint_as_float(((unsigned int)s) << 16);
}

// ---------------- conversion kernels ----------------
__global__ __launch_bounds__(256) void cvt_h_kernel(const float4* __restrict__ h4,
                                                    ushort4* __restrict__ hb4, int n4)
{
    int i = blockIdx.x * 256 + threadIdx.x;
    if (i < n4) {
        float4 v = h4[i];
        ushort4 o;
        o.x = f32_to_bf16_rne(v.x); o.y = f32_to_bf16_rne(v.y);
        o.z = f32_to_bf16_rne(v.z); o.w = f32_to_bf16_rne(v.w);
        hb4[i] = o;
    }
}

// Wt[r][o][k] = bf16(W[r][k][o])
__global__ __launch_bounds__(256) void cvt_w_kernel(const float* __restrict__ W,
                                                    unsigned short* __restrict__ Wt)
{
    int t = blockIdx.x * 256 + threadIdx.x;          // 16*64*64 threads
    int r = t >> 12, o = (t >> 6) & 63, k = t & 63;
    Wt[t] = f32_to_bf16_rne(W[(r << 12) + (k << 6) + o]);
}

// -------- fused: windowed fill(fillRange) + h-space aggregate+transform ------
// fill role: blocks [0,FILL_BLOCKS) scatter edges with dst in fillRange's
//   window into payF (window-relative buckets). Proven round-9/10 code.
// agg2 role: remaining blocks each own AGG_G=4 dst nodes of aggRange
//   (window filled by the PREVIOUS launch; stream order is the dependency).
//   Phase A: wave w = node base+w; lane k accumulates facc[r] = sum norm*h[src][k]
//   (rel is wave-uniform -> scalar switch, 1 fmac/edge). Stage to LDS.
//   Phase B: MFMA contraction over flattened rk (K=1024): out = hsum @ Wflat,
//   fragment layouts identical to the round-3-verified gemm. relu fused.
__global__ __launch_bounds__(256) void fill_agg2_kernel(
    const unsigned short* __restrict__ hb,   // [N][64] bf16
    const unsigned short* __restrict__ Wt,   // [16][o][k] bf16
    const int* __restrict__ src, const int* __restrict__ dst,
    const int* __restrict__ rel, const float* __restrict__ norm,
    int* __restrict__ cnt, int* __restrict__ ovfc, i32x4* __restrict__ ovf,
    i32x2* __restrict__ payF, const i32x2* __restrict__ payG,
    float* __restrict__ out, int fillRange, int aggRange)
{
    __shared__ float hsum[AGG_G][HS_STRIDE];         // 16.4 KB
    const int nFill = (fillRange >= 0) ? FILL_BLOCKS : 0;

    if ((int)blockIdx.x < nFill) {
        // ---- fill role ----
        const int lo = fillRange * NODES_PER_W, hi = lo + NODES_PER_W;
        for (int e = blockIdx.x * 256 + threadIdx.x; e < N_EDGES; e += nFill * 256) {
            int d = __builtin_nontemporal_load(&dst[e]);
            if (d >= lo && d < hi) {
                int s   = __builtin_nontemporal_load(&src[e]);
                int rl  = __builtin_nontemporal_load(&rel[e]);
                float nv = __builtin_nontemporal_load(&norm[e]);
                int pos = atomicAdd(&cnt[d], 1);
                if (pos < CAP) {
                    i32x2 p; p.x = (s << 4) | rl; p.y = __float_as_int(nv);
                    payF[(size_t)(d - lo) * CAP + pos] = p;
                } else {
                    int op = atomicAdd(ovfc, 1);
                    if (op < OVF_CAP) {
                        i32x4 o; o.x = d; o.y = (s << 4) | rl;
                        o.z = __float_as_int(nv); o.w = 0;
                        ovf[op] = o;
                    }
                }
            }
        }
        return;
    }

    // ---- agg2 role ----
    const int b     = blockIdx.x - nFill;
    const int winLo = aggRange * NODES_PER_W;
    const int base  = winLo + b * AGG_G;
    const int lane  = threadIdx.x & 63;
    const int w     = threadIdx.x >> 6;
    const int d     = base + w;                      // one node per wave

    // Phase A: accumulate facc[r][lane] = sum_e norm_e * h[src_e][lane]
    float facc[16];
    #pragma unroll
    for (int rr = 0; rr < 16; ++rr) facc[rr] = 0.f;

    const int degRaw = __builtin_amdgcn_readfirstlane(cnt[d]);
    const int deg    = min(degRaw, CAP);
    const i32x2* pp  = payG + (size_t)(d - winLo) * CAP;

    for (int i = 0; i < deg; ++i) {
        i32x2 p = pp[i];                             // same addr all lanes (L1 bcast)
        const int sx   = __builtin_amdgcn_readfirstlane(p.x);
        const float nv = __uint_as_float(
            (unsigned)__builtin_amdgcn_readfirstlane(p.y));
        const int s = sx >> 4;
        const int r = sx & 15;                       // wave-uniform (SGPR)
        const float hv = bf16_to_f32(hb[((size_t)s << 6) + lane]);
        const float c  = nv * hv;
        switch (r) {
            case 0:  facc[0]  += c; break;  case 1:  facc[1]  += c; break;
            case 2:  facc[2]  += c; break;  case 3:  facc[3]  += c; break;
            case 4:  facc[4]  += c; break;  case 5:  facc[5]  += c; break;
            case 6:  facc[6]  += c; break;  case 7:  facc[7]  += c; break;
            case 8:  facc[8]  += c; break;  case 9:  facc[9]  += c; break;
            case 10: facc[10] += c; break;  case 11: facc[11] += c; break;
            case 12: facc[12] += c; break;  case 13: facc[13] += c; break;
            case 14: facc[14] += c; break;  default: facc[15] += c; break;
        }
    }
    if (degRaw > CAP) {                              // exact overflow path (rare)
        const int no = min(__builtin_amdgcn_readfirstlane(*ovfc), OVF_CAP);
        for (int j = 0; j < no; ++j) {
            i32x4 o = ovf[j];
            if (o.x == d) {
                const int sx = o.y;
                const float nv = __uint_as_float((unsigned)o.z);
                const float hv = bf16_to_f32(hb[((size_t)(sx >> 4) << 6) + lane]);
                const float c  = nv * hv;
                switch (sx & 15) {
                    case 0:  facc[0]  += c; break;  case 1:  facc[1]  += c; break;
                    case 2:  facc[2]  += c; break;  case 3:  facc[3]  += c; break;
                    case 4:  facc[4]  += c; break;  case 5:  facc[5]  += c; break;
                    case 6:  facc[6]  += c; break;  case 7:  facc[7]  += c; break;
                    case 8:  facc[8]  += c; break;  case 9:  facc[9]  += c; break;
                    case 10: facc[10] += c; break;  case 11: facc[11] += c; break;
                    case 12: facc[12] += c; break;  case 13: facc[13] += c; break;
                    case 14: facc[14] += c; break;  default: facc[15] += c; break;
                }
            }
        }
    }
    // stage: hsum[node w][rk = r*64 + lane]
    #pragma unroll
    for (int rr = 0; rr < 16; ++rr)
        hsum[w][rr * 64 + lane] = facc[rr];
    __syncthreads();

    // Phase B: wave w computes o-tile [w*16, w*16+16) over K=1024 flattened rk.
    // A-frag: row q = node (q<AGG_G else 0), k-elems (lane>>4)*8..+8 of slice.
    // B-frag: Wt[r][o][k] with r=kk>>1, k=(kk&1)*32+(lane>>4)*8 (round-3 layout).
    const int q  = lane & 15;
    const int g4 = lane >> 4;
    f32x4 acc = {0.f, 0.f, 0.f, 0.f};
    const unsigned short* wb = Wt + ((size_t)(w * 16 + q) << 6) + (g4 << 3);
    for (int kk = 0; kk < 32; ++kk) {
        s16x8 af = {0, 0, 0, 0, 0, 0, 0, 0};
        if (q < AGG_G) {
            const float* hp = &hsum[q][kk * 32 + g4 * 8];
            f32x4 u0 = *reinterpret_cast<const f32x4*>(hp);
            f32x4 u1 = *reinterpret_cast<const f32x4*>(hp + 4);
            #pragma unroll
            for (int j = 0; j < 4; ++j) {
                af[j]     = (short)f32_to_bf16_rne(u0[j]);
                af[4 + j] = (short)f32_to_bf16_rne(u1[j]);
            }
        }
        s16x8 bf = *reinterpret_cast<const s16x8*>(
            wb + ((size_t)(kk >> 1) << 12) + ((kk & 1) << 5));
        acc = __builtin_amdgcn_mfma_f32_16x16x32_bf16(af, bf, acc, 0, 0, 0);
    }
    // C: col = t-local o = q, row = g4*4+reg; valid rows 0..3 live in g4==0
    if (g4 == 0) {
        #pragma unroll
        for (int rg = 0; rg < 4; ++rg)
            out[((size_t)(base + rg) << 6) + w * 16 + q] = fmaxf(acc[rg], 0.f);
    }
}

// ---------------- atomic fallback (no workspace) ----------------
__global__ __launch_bounds__(256) void rgcn_edge_kernel(
    const float* __restrict__ h, const float* __restrict__ W,
    const float* __restrict__ norm, const int* __restrict__ src,
    const int* __restrict__ dst, const int* __restrict__ rel,
    float* __restrict__ out)
{
    const int lane = threadIdx.x & 63;
    const int w    = threadIdx.x >> 6;
    const int r    = blockIdx.x & 15;
    const int inst = blockIdx.x >> 4;
    const int wavesPerRel = (gridDim.x >> 4) * 4;
    const int wi   = inst * 4 + w;

    float wreg[64];
    const float* Wr = W + (size_t)r * (FEAT * FEAT) + lane;
    #pragma unroll
    for (int d = 0; d < 64; ++d) wreg[d] = Wr[d * 64];

    const int nChunks = N_EDGES / 64;
    for (int c = wi; c < nChunks; c += wavesPerRel) {
        const int base = c * 64;
        unsigned long long m = __ballot(rel[base + lane] == r);
        while (m) {
            const int idx = __ffsll(m) - 1;
            m &= (m - 1);
            const int e = base + idx;
            const int se = __builtin_amdgcn_readfirstlane(src[e]);
            const int de = __builtin_amdgcn_readfirstlane(dst[e]);
            const float nv = __uint_as_float(
                __builtin_amdgcn_readfirstlane(__float_as_uint(norm[e])));
            const float* hp = h + ((size_t)se << 6);
            f32x16 ha, hb2, hc, hd;
            asm volatile(
                "s_load_dwordx16 %0, %4, 0x0\n\ts_load_dwordx16 %1, %4, 0x40\n\t"
                "s_load_dwordx16 %2, %4, 0x80\n\ts_load_dwordx16 %3, %4, 0xc0\n\t"
                "s_waitcnt lgkmcnt(0)"
                : "=&s"(ha), "=&s"(hb2), "=&s"(hc), "=&s"(hd) : "s"(hp));
            float a0 = 0.f, a1 = 0.f, a2 = 0.f, a3 = 0.f;
            #pragma unroll
            for (int j = 0; j < 16; ++j) {
                a0 = fmaf(ha[j], wreg[j], a0);       a1 = fmaf(hb2[j], wreg[16 + j], a1);
                a2 = fmaf(hc[j], wreg[32 + j], a2);  a3 = fmaf(hd[j], wreg[48 + j], a3);
            }
            unsafeAtomicAdd(&out[(size_t)de * FEAT + lane], ((a0 + a1) + (a2 + a3)) * nv);
        }
    }
}

__global__ __launch_bounds__(256) void relu_kernel(float4* __restrict__ out, int n4)
{
    int i = blockIdx.x * 256 + threadIdx.x;
    if (i < n4) {
        float4 v = out[i];
        v.x = fmaxf(v.x, 0.f); v.y = fmaxf(v.y, 0.f);
        v.z = fmaxf(v.z, 0.f); v.w = fmaxf(v.w, 0.f);
        out[i] = v;
    }
}

// ---------------- host ----------------
static inline size_t align256(size_t x) { return (x + 255) & ~(size_t)255; }

extern "C" void kernel_launch(void* const* d_in, const int* in_sizes, int n_in,
                              void* d_out, int out_size, void* d_ws, size_t ws_size,
                              hipStream_t stream)
{
    (void)in_sizes; (void)n_in;

    const float* h    = (const float*)d_in[0];
    const float* W    = (const float*)d_in[1];
    const float* norm = (const float*)d_in[2];
    const int*   src  = (const int*)d_in[3];
    const int*   dst  = (const int*)d_in[4];
    const int*   rel  = (const int*)d_in[5];
    float*       out  = (float*)d_out;

    const size_t szHb   = (size_t)N_NODES * FEAT * 2;              // 12.8 MB
    const size_t szWt   = (size_t)NUM_RELS * FEAT * FEAT * 2;      // 128 KB
    const size_t szCnt  = (size_t)N_NODES * 4;                     // 400 KB
    const size_t szPayW = (size_t)NODES_PER_W * CAP * 8;           // 12.8 MB / window
    const size_t szOvf  = (size_t)OVF_CAP * 16;                    // 512 KB

    const size_t need = align256(szHb) + align256(szWt) + 2 * align256(szPayW)
                      + align256(szCnt) + align256(256) + align256(szOvf); // ~40 MB

    const int n4h = N_NODES * FEAT / 4;

    if (ws_size >= need) {
        char* ws = (char*)d_ws; size_t off = 0;
        unsigned short* hb   = (unsigned short*)(ws + off); off += align256(szHb);
        unsigned short* Wt   = (unsigned short*)(ws + off); off += align256(szWt);
        i32x2*          pay0 = (i32x2*)         (ws + off); off += align256(szPayW);
        i32x2*          pay1 = (i32x2*)         (ws + off); off += align256(szPayW);
        int*            cnt  = (int*)           (ws + off); off += align256(szCnt);
        int*            ovfc = (int*)           (ws + off); off += align256(256);
        i32x4*          ovf  = (i32x4*)         (ws + off); off += align256(szOvf);

        hipLaunchKernelGGL(cvt_h_kernel, dim3((n4h + 255) / 256), dim3(256), 0, stream,
                           (const float4*)h, (ushort4*)hb, n4h);
        hipLaunchKernelGGL(cvt_w_kernel, dim3(NUM_RELS * FEAT * FEAT / 256), dim3(256),
                           0, stream, W, Wt);
        hipMemsetAsync(cnt, 0, szCnt, stream);
        hipMemsetAsync(ovfc, 0, 256, stream);

        // K0: fill(0); K1..K3: fill(r) + agg2(r-1); K4: agg2(3).
        i32x2* win[2] = {pay0, pay1};
        hipLaunchKernelGGL(fill_agg2_kernel, dim3(FILL_BLOCKS), dim3(256), 0, stream,
                           hb, Wt, src, dst, rel, norm, cnt, ovfc, ovf,
                           win[0], (const i32x2*)nullptr, out, 0, -1);
        for (int r = 1; r < RANGES_W; ++r) {
            hipLaunchKernelGGL(fill_agg2_kernel, dim3(FILL_BLOCKS + AGG_BLOCKS), dim3(256),
                               0, stream, hb, Wt, src, dst, rel, norm, cnt, ovfc, ovf,
                               win[r & 1], win[(r - 1) & 1], out, r, r - 1);
        }
        hipLaunchKernelGGL(fill_agg2_kernel, dim3(AGG_BLOCKS), dim3(256), 0, stream,
                           hb, Wt, src, dst, rel, norm, cnt, ovfc, ovf,
                           (i32x2*)nullptr, win[(RANGES_W - 1) & 1], out,
                           -1, RANGES_W - 1);
        return;
    }

    // last-resort atomic path
    hipMemsetAsync(d_out, 0, (size_t)out_size * sizeof(float), stream);
    hipLaunchKernelGGL(rgcn_edge_kernel, dim3(16 * 128), dim3(256), 0, stream,
                       h, W, norm, src, dst, rel, out);
    const int n4 = out_size / 4;
    hipLaunchKernelGGL(relu_kernel, dim3((n4 + 255) / 256), dim3(256), 0, stream,
                       (float4*)d_out, n4);
}

// Round 13
// 738.973 us; speedup vs baseline: 1.0628x; 1.0628x over previous
//
#include <hip/hip_runtime.h>

#define N_NODES 100000
#define N_EDGES 3200000
#define FEAT 64
#define NUM_RELS 16
#define CAP_R 8                 // slots per (dst, rel); Poisson(2) P(>8)=2.4e-4
#define OVF_CAP 32768
#define RANGES_W 4
#define NODES_PER_W 25000       // N_NODES / RANGES_W exact
#define FILL_BLOCKS 1024
#define AGG_G 4                 // nodes per agg block (1 per wave)
#define AGG_BLOCKS (NODES_PER_W / AGG_G)   // 6250
#define HS_STRIDE 1028          // floats; pad avoids systematic bank aliasing

typedef float f32x4 __attribute__((ext_vector_type(4)));
typedef float f32x16 __attribute__((ext_vector_type(16)));
typedef short s16x8 __attribute__((ext_vector_type(8)));
typedef int   i32x2 __attribute__((ext_vector_type(2)));
typedef int   i32x4 __attribute__((ext_vector_type(4)));

__device__ __forceinline__ unsigned short f32_to_bf16_rne(float x) {
    unsigned int u = __float_as_uint(x);
    unsigned int r = (u + 0x7fffu + ((u >> 16) & 1u)) >> 16;
    return (unsigned short)r;
}
__device__ __forceinline__ float bf16_to_f32(unsigned short s) {
    return __uint_as_float(((unsigned int)s) << 16);
}
__device__ __forceinline__ int rfl(int v) { return __builtin_amdgcn_readfirstlane(v); }
__device__ __forceinline__ float rflf(int v) {
    return __uint_as_float((unsigned)__builtin_amdgcn_readfirstlane(v));
}

// ---------------- conversion kernels ----------------
__global__ __launch_bounds__(256) void cvt_h_kernel(const float4* __restrict__ h4,
                                                    ushort4* __restrict__ hb4, int n4)
{
    int i = blockIdx.x * 256 + threadIdx.x;
    if (i < n4) {
        float4 v = h4[i];
        ushort4 o;
        o.x = f32_to_bf16_rne(v.x); o.y = f32_to_bf16_rne(v.y);
        o.z = f32_to_bf16_rne(v.z); o.w = f32_to_bf16_rne(v.w);
        hb4[i] = o;
    }
}

// Wt[r][o][k] = bf16(W[r][k][o])
__global__ __launch_bounds__(256) void cvt_w_kernel(const float* __restrict__ W,
                                                    unsigned short* __restrict__ Wt)
{
    int t = blockIdx.x * 256 + threadIdx.x;          // 16*64*64 threads
    int r = t >> 12, o = (t >> 6) & 63, k = t & 63;
    Wt[t] = f32_to_bf16_rne(W[(r << 12) + (k << 6) + o]);
}

// -------- fused: windowed rel-segmented fill + h-space aggregate+transform ---
// fill role: blocks [0,FILL_BLOCKS): edge e with dst in window -> slot
//   pay[((d-lo)*16 + rel)*CAP_R + pos], pos from atomicAdd(cnt[d*16+rel]).
//   Rel-segmented buckets make Phase A branch-free (no per-edge rel switch).
// agg role: wave = one node. Phase A: 16 static per-rel segment loops, 2x ILP,
//   facc[r] statically indexed (outer loop fully unrolled). Phase B: MFMA
//   contraction over flattened rk (K=1024), layouts verified in round 12.
__global__ __launch_bounds__(256) void fill_agg2_kernel(
    const unsigned short* __restrict__ hb,   // [N][64] bf16
    const unsigned short* __restrict__ Wt,   // [16][o][k] bf16
    const int* __restrict__ src, const int* __restrict__ dst,
    const int* __restrict__ rel, const float* __restrict__ norm,
    int* __restrict__ cnt,                   // [N][16]
    int* __restrict__ ovfc, i32x4* __restrict__ ovf,
    i32x2* __restrict__ payF, const i32x2* __restrict__ payG,
    float* __restrict__ out, int fillRange, int aggRange)
{
    __shared__ float hsum[AGG_G][HS_STRIDE];         // 16.4 KB
    const int nFill = (fillRange >= 0) ? FILL_BLOCKS : 0;

    if ((int)blockIdx.x < nFill) {
        // ---- fill role ----
        const int lo = fillRange * NODES_PER_W, hi = lo + NODES_PER_W;
        for (int e = blockIdx.x * 256 + threadIdx.x; e < N_EDGES; e += nFill * 256) {
            int d = __builtin_nontemporal_load(&dst[e]);
            if (d >= lo && d < hi) {
                int s   = __builtin_nontemporal_load(&src[e]);
                int rl  = __builtin_nontemporal_load(&rel[e]);
                float nv = __builtin_nontemporal_load(&norm[e]);
                int pos = atomicAdd(&cnt[(size_t)d * 16 + rl], 1);
                if (pos < CAP_R) {
                    i32x2 p; p.x = s; p.y = __float_as_int(nv);
                    payF[((size_t)(d - lo) * 16 + rl) * CAP_R + pos] = p;
                } else {
                    int op = atomicAdd(ovfc, 1);
                    if (op < OVF_CAP) {
                        i32x4 o; o.x = d; o.y = (s << 4) | rl;
                        o.z = __float_as_int(nv); o.w = 0;
                        ovf[op] = o;
                    }
                }
            }
        }
        return;
    }

    // ---- agg role ----
    const int b     = blockIdx.x - nFill;
    const int winLo = aggRange * NODES_PER_W;
    const int base  = winLo + b * AGG_G;
    const int lane  = threadIdx.x & 63;
    const int w     = threadIdx.x >> 6;
    const int d     = base + w;                      // one node per wave

    // load the 16 per-rel counts (wave-uniform)
    const int* cd = cnt + (size_t)d * 16;
    int cs[16];
    bool anyOvf = false;
    {
        i32x4 c0 = *reinterpret_cast<const i32x4*>(cd);
        i32x4 c1 = *reinterpret_cast<const i32x4*>(cd + 4);
        i32x4 c2 = *reinterpret_cast<const i32x4*>(cd + 8);
        i32x4 c3 = *reinterpret_cast<const i32x4*>(cd + 12);
        #pragma unroll
        for (int j = 0; j < 4; ++j) {
            cs[j]      = rfl(c0[j]);  cs[4 + j]  = rfl(c1[j]);
            cs[8 + j]  = rfl(c2[j]);  cs[12 + j] = rfl(c3[j]);
        }
        #pragma unroll
        for (int r = 0; r < 16; ++r) anyOvf |= (cs[r] > CAP_R);
    }

    // Phase A: branch-free per-rel segment accumulation (static facc index)
    float facc[16];
    const i32x2* pb = payG + (size_t)(d - winLo) * (16 * CAP_R);
    #pragma unroll
    for (int r = 0; r < 16; ++r) {
        const i32x2* ps = pb + r * CAP_R;
        const int n = min(cs[r], CAP_R);
        float acc = 0.f;
        int i = 0;
        for (; i + 2 <= n; i += 2) {
            i32x2 p0 = ps[i], p1 = ps[i + 1];
            const int   s0 = rfl(p0.x), s1 = rfl(p1.x);
            const float n0 = rflf(p0.y), n1 = rflf(p1.y);
            const float h0 = bf16_to_f32(hb[((size_t)s0 << 6) + lane]);
            const float h1 = bf16_to_f32(hb[((size_t)s1 << 6) + lane]);
            acc = fmaf(n0, h0, acc);
            acc = fmaf(n1, h1, acc);
        }
        if (i < n) {
            i32x2 p0 = ps[i];
            const int   s0 = rfl(p0.x);
            const float n0 = rflf(p0.y);
            acc = fmaf(n0, bf16_to_f32(hb[((size_t)s0 << 6) + lane]), acc);
        }
        facc[r] = acc;
    }
    if (anyOvf) {                                    // exact overflow path (rare)
        const int no = min(rfl(*ovfc), OVF_CAP);
        for (int j = 0; j < no; ++j) {
            i32x4 o = ovf[j];
            if (o.x == d) {
                const int sx = o.y;
                const float nv = __uint_as_float((unsigned)o.z);
                const float c  = nv * bf16_to_f32(hb[((size_t)(sx >> 4) << 6) + lane]);
                switch (sx & 15) {
                    case 0:  facc[0]  += c; break;  case 1:  facc[1]  += c; break;
                    case 2:  facc[2]  += c; break;  case 3:  facc[3]  += c; break;
                    case 4:  facc[4]  += c; break;  case 5:  facc[5]  += c; break;
                    case 6:  facc[6]  += c; break;  case 7:  facc[7]  += c; break;
                    case 8:  facc[8]  += c; break;  case 9:  facc[9]  += c; break;
                    case 10: facc[10] += c; break;  case 11: facc[11] += c; break;
                    case 12: facc[12] += c; break;  case 13: facc[13] += c; break;
                    case 14: facc[14] += c; break;  default: facc[15] += c; break;
                }
            }
        }
    }
    // stage: hsum[node w][rk = r*64 + lane]
    #pragma unroll
    for (int rr = 0; rr < 16; ++rr)
        hsum[w][rr * 64 + lane] = facc[rr];
    __syncthreads();

    // Phase B (round-12 verified): wave w -> o-tile [w*16, w*16+16), K=1024.
    const int q  = lane & 15;
    const int g4 = lane >> 4;
    f32x4 acc = {0.f, 0.f, 0.f, 0.f};
    const unsigned short* wb = Wt + ((size_t)(w * 16 + q) << 6) + (g4 << 3);
    for (int kk = 0; kk < 32; ++kk) {
        s16x8 af = {0, 0, 0, 0, 0, 0, 0, 0};
        if (q < AGG_G) {
            const float* hp = &hsum[q][kk * 32 + g4 * 8];
            f32x4 u0 = *reinterpret_cast<const f32x4*>(hp);
            f32x4 u1 = *reinterpret_cast<const f32x4*>(hp + 4);
            #pragma unroll
            for (int j = 0; j < 4; ++j) {
                af[j]     = (short)f32_to_bf16_rne(u0[j]);
                af[4 + j] = (short)f32_to_bf16_rne(u1[j]);
            }
        }
        s16x8 bf = *reinterpret_cast<const s16x8*>(
            wb + ((size_t)(kk >> 1) << 12) + ((kk & 1) << 5));
        acc = __builtin_amdgcn_mfma_f32_16x16x32_bf16(af, bf, acc, 0, 0, 0);
    }
    if (g4 == 0) {
        #pragma unroll
        for (int rg = 0; rg < 4; ++rg)
            out[((size_t)(base + rg) << 6) + w * 16 + q] = fmaxf(acc[rg], 0.f);
    }
}

// ---------------- atomic fallback (no workspace) ----------------
__global__ __launch_bounds__(256) void rgcn_edge_kernel(
    const float* __restrict__ h, const float* __restrict__ W,
    const float* __restrict__ norm, const int* __restrict__ src,
    const int* __restrict__ dst, const int* __restrict__ rel,
    float* __restrict__ out)
{
    const int lane = threadIdx.x & 63;
    const int w    = threadIdx.x >> 6;
    const int r    = blockIdx.x & 15;
    const int inst = blockIdx.x >> 4;
    const int wavesPerRel = (gridDim.x >> 4) * 4;
    const int wi   = inst * 4 + w;

    float wreg[64];
    const float* Wr = W + (size_t)r * (FEAT * FEAT) + lane;
    #pragma unroll
    for (int d = 0; d < 64; ++d) wreg[d] = Wr[d * 64];

    const int nChunks = N_EDGES / 64;
    for (int c = wi; c < nChunks; c += wavesPerRel) {
        const int base = c * 64;
        unsigned long long m = __ballot(rel[base + lane] == r);
        while (m) {
            const int idx = __ffsll(m) - 1;
            m &= (m - 1);
            const int e = base + idx;
            const int se = __builtin_amdgcn_readfirstlane(src[e]);
            const int de = __builtin_amdgcn_readfirstlane(dst[e]);
            const float nv = __uint_as_float(
                __builtin_amdgcn_readfirstlane(__float_as_uint(norm[e])));
            const float* hp = h + ((size_t)se << 6);
            f32x16 ha, hb2, hc, hd;
            asm volatile(
                "s_load_dwordx16 %0, %4, 0x0\n\ts_load_dwordx16 %1, %4, 0x40\n\t"
                "s_load_dwordx16 %2, %4, 0x80\n\ts_load_dwordx16 %3, %4, 0xc0\n\t"
                "s_waitcnt lgkmcnt(0)"
                : "=&s"(ha), "=&s"(hb2), "=&s"(hc), "=&s"(hd) : "s"(hp));
            float a0 = 0.f, a1 = 0.f, a2 = 0.f, a3 = 0.f;
            #pragma unroll
            for (int j = 0; j < 16; ++j) {
                a0 = fmaf(ha[j], wreg[j], a0);       a1 = fmaf(hb2[j], wreg[16 + j], a1);
                a2 = fmaf(hc[j], wreg[32 + j], a2);  a3 = fmaf(hd[j], wreg[48 + j], a3);
            }
            unsafeAtomicAdd(&out[(size_t)de * FEAT + lane], ((a0 + a1) + (a2 + a3)) * nv);
        }
    }
}

__global__ __launch_bounds__(256) void relu_kernel(float4* __restrict__ out, int n4)
{
    int i = blockIdx.x * 256 + threadIdx.x;
    if (i < n4) {
        float4 v = out[i];
        v.x = fmaxf(v.x, 0.f); v.y = fmaxf(v.y, 0.f);
        v.z = fmaxf(v.z, 0.f); v.w = fmaxf(v.w, 0.f);
        out[i] = v;
    }
}

// ---------------- host ----------------
static inline size_t align256(size_t x) { return (x + 255) & ~(size_t)255; }

extern "C" void kernel_launch(void* const* d_in, const int* in_sizes, int n_in,
                              void* d_out, int out_size, void* d_ws, size_t ws_size,
                              hipStream_t stream)
{
    (void)in_sizes; (void)n_in;

    const float* h    = (const float*)d_in[0];
    const float* W    = (const float*)d_in[1];
    const float* norm = (const float*)d_in[2];
    const int*   src  = (const int*)d_in[3];
    const int*   dst  = (const int*)d_in[4];
    const int*   rel  = (const int*)d_in[5];
    float*       out  = (float*)d_out;

    const size_t szHb   = (size_t)N_NODES * FEAT * 2;              // 12.8 MB
    const size_t szWt   = (size_t)NUM_RELS * FEAT * FEAT * 2;      // 128 KB
    const size_t szCnt  = (size_t)N_NODES * NUM_RELS * 4;          // 6.4 MB
    const size_t szPayW = (size_t)NODES_PER_W * NUM_RELS * CAP_R * 8; // 25.6 MB
    const size_t szOvf  = (size_t)OVF_CAP * 16;                    // 512 KB

    const size_t need = align256(szHb) + align256(szWt) + 2 * align256(szPayW)
                      + align256(szCnt) + align256(256) + align256(szOvf); // ~71 MB

    const int n4h = N_NODES * FEAT / 4;

    if (ws_size >= need) {
        char* ws = (char*)d_ws; size_t off = 0;
        unsigned short* hb   = (unsigned short*)(ws + off); off += align256(szHb);
        unsigned short* Wt   = (unsigned short*)(ws + off); off += align256(szWt);
        i32x2*          pay0 = (i32x2*)         (ws + off); off += align256(szPayW);
        i32x2*          pay1 = (i32x2*)         (ws + off); off += align256(szPayW);
        int*            cnt  = (int*)           (ws + off); off += align256(szCnt);
        int*            ovfc = (int*)           (ws + off); off += align256(256);
        i32x4*          ovf  = (i32x4*)         (ws + off); off += align256(szOvf);

        hipLaunchKernelGGL(cvt_h_kernel, dim3((n4h + 255) / 256), dim3(256), 0, stream,
                           (const float4*)h, (ushort4*)hb, n4h);
        hipLaunchKernelGGL(cvt_w_kernel, dim3(NUM_RELS * FEAT * FEAT / 256), dim3(256),
                           0, stream, W, Wt);
        hipMemsetAsync(cnt, 0, szCnt, stream);
        hipMemsetAsync(ovfc, 0, 256, stream);

        // K0: fill(0); K1..K3: fill(r) + agg(r-1); K4: agg(3).
        i32x2* win[2] = {pay0, pay1};
        hipLaunchKernelGGL(fill_agg2_kernel, dim3(FILL_BLOCKS), dim3(256), 0, stream,
                           hb, Wt, src, dst, rel, norm, cnt, ovfc, ovf,
                           win[0], (const i32x2*)nullptr, out, 0, -1);
        for (int r = 1; r < RANGES_W; ++r) {
            hipLaunchKernelGGL(fill_agg2_kernel, dim3(FILL_BLOCKS + AGG_BLOCKS), dim3(256),
                               0, stream, hb, Wt, src, dst, rel, norm, cnt, ovfc, ovf,
                               win[r & 1], win[(r - 1) & 1], out, r, r - 1);
        }
        hipLaunchKernelGGL(fill_agg2_kernel, dim3(AGG_BLOCKS), dim3(256), 0, stream,
                           hb, Wt, src, dst, rel, norm, cnt, ovfc, ovf,
                           (i32x2*)nullptr, win[(RANGES_W - 1) & 1], out,
                           -1, RANGES_W - 1);
        return;
    }

    // last-resort atomic path
    hipMemsetAsync(d_out, 0, (size_t)out_size * sizeof(float), stream);
    hipLaunchKernelGGL(rgcn_edge_kernel, dim3(16 * 128), dim3(256), 0, stream,
                       h, W, norm, src, dst, rel, out);
    const int n4 = out_size / 4;
    hipLaunchKernelGGL(relu_kernel, dim3((n4 + 255) / 256), dim3(256), 0, stream,
                       (float4*)d_out, n4);
}